// Round 4
// baseline (300.928 us; speedup 1.0000x reference)
//
#include <hip/hip_runtime.h>

typedef float f4 __attribute__((ext_vector_type(4)));

#define Wd 1024
#define Hd 1024
#define SH 16            // output rows per block; 1024 blocks = 4/CU (halo re-reads are L3 hits)
#define ITER (SH + 6)    // input (lum) rows streamed per block

// Barrier-free, LDS-free: horizontal halo comes from each thread's own
// overlapping global loads (o-4, o, o+4 per channel). Overlap bytes are
// same-cache-line within the wave -> L1 hits, no extra HBM. Waves free-run;
// full unroll lets the compiler pipeline loads across rows (fills prove
// ~6.7 TB/s at 10% occupancy in exactly this regime).
__global__ __launch_bounds__(256, 4)
void lvm_stream(const float* __restrict__ x, float* __restrict__ out) {
    const int b    = blockIdx.y;
    const int row0 = blockIdx.x * SH;
    const int tid  = threadIdx.x;
    const int c0   = tid * 4;

    const float* x0 = x + (size_t)b * 3 * Hd * Wd;
    const float* x1 = x0 + (size_t)Hd * Wd;
    const float* x2 = x1 + (size_t)Hd * Wd;
    float*       ob = out + (size_t)b * Hd * Wd;

    // edge lanes: clamp halo-load address into the row (avoid OOB), then
    // zero the halo values via loop-invariant selects (cndmask, no branch)
    const bool eL = (c0 == 0);
    const bool eR = (c0 == Wd - 4);
    const int  dL = eL ? 0 : -4;
    const int  dR = eR ? 0 :  4;

    f4 ring1[7], ring2[7];   // per-thread 7-row ring of horizontal sums (static idx)

#pragma unroll
    for (int i = 0; i < ITER; ++i) {
        const int ri = row0 - 3 + i;          // input (lum) row
        float v1 = 0.f, v2 = 0.f, v3 = 0.f, v4 = 0.f, v5 = 0.f;
        float v6 = 0.f, v7 = 0.f, v8 = 0.f, v9 = 0.f, v10 = 0.f;
        if (ri >= 0 && ri < Hd) {             // wave-uniform
            const size_t o = (size_t)ri * Wd + c0;
            f4 aC = *(const f4*)(x0 + o);
            f4 gC = *(const f4*)(x1 + o);
            f4 cC = *(const f4*)(x2 + o);
            f4 aL = *(const f4*)(x0 + o + dL);
            f4 gL = *(const f4*)(x1 + o + dL);
            f4 cL = *(const f4*)(x2 + o + dL);
            f4 aR = *(const f4*)(x0 + o + dR);
            f4 gR = *(const f4*)(x1 + o + dR);
            f4 cR = *(const f4*)(x2 + o + dR);
            f4 lumC = (aC + gC + cC) * (1.f / 3.f);
            f4 lumL = (aL + gL + cL) * (1.f / 3.f);
            f4 lumR = (aR + gR + cR) * (1.f / 3.f);
            v4 = lumC.x; v5 = lumC.y; v6 = lumC.z; v7 = lumC.w;
            v1  = eL ? 0.f : lumL.y;          // col c0-3
            v2  = eL ? 0.f : lumL.z;          // col c0-2
            v3  = eL ? 0.f : lumL.w;          // col c0-1
            v8  = eR ? 0.f : lumR.x;          // col c0+4
            v9  = eR ? 0.f : lumR.y;          // col c0+5
            v10 = eR ? 0.f : lumR.z;          // col c0+6
        }

        // horizontal 7-tap sums, sliding window across the 4 output columns
        float s1a = v1 + v2 + v3 + v4 + v5 + v6 + v7;
        float s1b = s1a - v1 + v8;
        float s1c = s1b - v2 + v9;
        float s1d = s1c - v3 + v10;

        float q1 = v1 * v1, q2 = v2 * v2, q3 = v3 * v3, q4 = v4 * v4;
        float q5 = v5 * v5, q6 = v6 * v6, q7 = v7 * v7, q8 = v8 * v8;
        float q9 = v9 * v9, q10 = v10 * v10;
        float s2a = q1 + q2 + q3 + q4 + q5 + q6 + q7;
        float s2b = s2a - q1 + q8;
        float s2c = s2b - q2 + q9;
        float s2d = s2c - q3 + q10;

        ring1[i % 7] = (f4){s1a, s1b, s1c, s1d};   // i compile-time (full unroll)
        ring2[i % 7] = (f4){s2a, s2b, s2c, s2d};

        if (i >= 6) {                          // ring full -> emit output row
            f4 t1 = ring1[0], t2 = ring2[0];
#pragma unroll
            for (int k = 1; k < 7; ++k) { t1 += ring1[k]; t2 += ring2[k]; }
            const float inv = 1.f / 49.f;
            f4 m = t1 * inv;
            f4 r = t2 * inv - m * m;
            const int ro = row0 + i - 6;
            // output never re-read: keep L2/L3 for the input halo
            __builtin_nontemporal_store(r, (f4*)(ob + (size_t)ro * Wd + c0));
        }
    }
}

extern "C" void kernel_launch(void* const* d_in, const int* in_sizes, int n_in,
                              void* d_out, int out_size, void* d_ws, size_t ws_size,
                              hipStream_t stream) {
    const float* x = (const float*)d_in[0];
    float* out = (float*)d_out;
    dim3 grid(Hd / SH, 16);   // 64 row-strips x 16 batches = 1024 blocks
    lvm_stream<<<grid, dim3(256), 0, stream>>>(x, out);
}